// Round 8
// baseline (399.900 us; speedup 1.0000x reference)
//
#include <hip/hip_runtime.h>

#define B_ 4
#define C_ 256
#define CQK 64
#define N_ 4096
#define SEG 2
#define SEGN (N_ / SEG)    // 2048
#define NB 128
#define ITERS (SEGN / NB)  // 16
#define TS 512             // elements per 16x32 fragment tile (1 KB)
#define NBLK 512           // fused grid size; == 2 blocks/CU * 256 CUs

typedef _Float16 f16;
typedef __attribute__((ext_vector_type(8))) _Float16 f16x8;
typedef __attribute__((ext_vector_type(4))) _Float16 f16x4;
typedef __attribute__((ext_vector_type(4))) float f32x4;
typedef __attribute__((ext_vector_type(4))) float float4v;

#define TILE_OFF(l15, quad) ((l15) * 32 + (quad) * 8)

// Grid barrier for a fully-resident grid (NBLK blocks, guaranteed by
// __launch_bounds__(256,2): 2 blocks/CU schedulable on 256 CUs = 512).
// arrival: device-scope atomicAdd; release: generation bump; spin uses
// __hip_atomic_load at AGENT scope (coherent across XCD L2s — a volatile
// load could spin on a stale line forever). threadfence makes phase-N
// global stores visible to phase-N+1 readers on other XCDs.
__device__ __forceinline__ void gridbar(unsigned* bar) {
  __syncthreads();
  if (threadIdx.x == 0) {
    __threadfence();
    unsigned gen = __hip_atomic_load(bar + 1, __ATOMIC_RELAXED, __HIP_MEMORY_SCOPE_AGENT);
    unsigned old = atomicAdd(bar, 1u);
    if (old == NBLK - 1) {
      __hip_atomic_store(bar, 0u, __ATOMIC_RELAXED, __HIP_MEMORY_SCOPE_AGENT);
      __hip_atomic_fetch_add(bar + 1, 1u, __ATOMIC_RELEASE, __HIP_MEMORY_SCOPE_AGENT);
    } else {
      while (__hip_atomic_load(bar + 1, __ATOMIC_ACQUIRE, __HIP_MEMORY_SCOPE_AGENT) == gen)
        __builtin_amdgcn_s_sleep(2);
    }
    __threadfence();
  }
  __syncthreads();
}

// ---------------- fused: prep_w -> proj -> attn -> combine ----------------
// r5-r7 established: attn is hardened at ~61us; three different proj
// implementations all left non-attn time at ~95-100us => the cost is the
// 4 kernel-boundary overheads (~12-16us each), not the kernel bodies.
// This kernel removes all boundaries. Phase bodies are verbatim from the
// harness-verified r7 kernels; only blockIdx decomposition changed.
__global__ __launch_bounds__(256, 2) void fused(
    const float* __restrict__ x, const float* __restrict__ wq,
    const float* __restrict__ bq, const float* __restrict__ wk,
    const float* __restrict__ bk, const float* __restrict__ wv,
    const float* __restrict__ bv, const float* __restrict__ wg,
    const float* __restrict__ bg, f16* __restrict__ QTt, f16* __restrict__ KTt,
    f16* __restrict__ Vt, f16* __restrict__ WQt, f16* __restrict__ WKt,
    f16* __restrict__ WVt, f16* __restrict__ WGt, f16* __restrict__ part,
    float* __restrict__ out, unsigned* __restrict__ bar) {
  __shared__ __align__(16) union {
    struct { float xs[32][265]; f16 xt[2 * 8 * TS]; } p;  // proj stage (49.1 KB)
    f16 sPt[2][64][128];                                  // attn P^T dbuf / O buf
  } sh;
  int bid = blockIdx.x;
  int tid = threadIdx.x, lane = tid & 63, w = tid >> 6;
  int l15 = lane & 15, quad = lane >> 4;

  // ================= phase 0: prep_w (threads 0..20479) =================
  {
    int chunk = bid * 256 + tid;
    if (chunk < 20480) {
      const float* src;
      f16* dst;
      int lo;
      if (chunk < 2048) { src = wq; dst = WQt; lo = chunk * 8; }
      else if (chunk < 4096) { src = wk; dst = WKt; lo = (chunk - 2048) * 8; }
      else if (chunk < 12288) { src = wv; dst = WVt; lo = (chunk - 4096) * 8; }
      else { src = wg; dst = WGt; lo = (chunk - 12288) * 8; }
      int o = lo >> 8, k = lo & 255;
      f16x8 v;
#pragma unroll
      for (int j = 0; j < 8; j++) v[j] = (f16)src[lo + j];
      *(f16x8*)(dst + ((size_t)(o >> 4) * 8 + (k >> 5)) * TS + (o & 15) * 32 +
                (k & 31)) = v;
    }
  }
  gridbar(bar);

  // ================= phase 1: proj (nx = bid&127, b = bid>>7) =================
  {
    int n0 = (bid & 127) * 32;
    int b = bid >> 7;
    const float* xb = x + (size_t)b * C_ * N_;

    // stage 1: load 256c x 32n, float4 along n, store transposed
#pragma unroll
    for (int i = 0; i < 8; i++) {
      int c = i * 32 + (tid >> 3);
      int n4 = (tid & 7) * 4;
      float4v f4 = *(const float4v*)(xb + (size_t)c * N_ + n0 + n4);
#pragma unroll
      for (int j = 0; j < 4; j++) sh.p.xs[n4 + j][c] = f4[j];
    }
    __syncthreads();
    // stage 2: repack to f16 fragment tiles
#pragma unroll
    for (int i = 0; i < 4; i++) {
      int t = w + i * 4;
      int nt = t >> 3, kt = t & 7;
      f16x8 v;
#pragma unroll
      for (int j = 0; j < 8; j++)
        v[j] = (f16)sh.p.xs[nt * 16 + l15][kt * 32 + quad * 8 + j];
      *(f16x8*)(sh.p.xt + (nt * 8 + kt) * TS + l15 * 32 + quad * 8) = v;
    }
    __syncthreads();

    f32x4 acc[6][2];
#pragma unroll
    for (int j = 0; j < 6; j++)
#pragma unroll
      for (int nt = 0; nt < 2; nt++) acc[j][nt] = (f32x4){0.f, 0.f, 0.f, 0.f};

#pragma unroll
    for (int kt = 0; kt < 8; kt++) {
      f16x8 xf[2];
#pragma unroll
      for (int nt = 0; nt < 2; nt++)
        xf[nt] = *(const f16x8*)(sh.p.xt + (nt * 8 + kt) * TS + TILE_OFF(l15, quad));
#pragma unroll
      for (int j = 0; j < 6; j++) {
        int g = w * 6 + j;
        const f16* Wt;
        int ot;
        bool isV = g < 16;
        if (isV) { Wt = WVt; ot = g; }
        else if (g < 20) { Wt = WQt; ot = g - 16; }
        else { Wt = WKt; ot = g - 20; }
        f16x8 wf = *(const f16x8*)(Wt + ((size_t)ot * 8 + kt) * TS + TILE_OFF(l15, quad));
#pragma unroll
        for (int nt = 0; nt < 2; nt++)
          acc[j][nt] = isV
              ? __builtin_amdgcn_mfma_f32_16x16x32_f16(xf[nt], wf, acc[j][nt], 0, 0, 0)
              : __builtin_amdgcn_mfma_f32_16x16x32_f16(wf, xf[nt], acc[j][nt], 0, 0, 0);
      }
    }

    f16* vbout = Vt + (size_t)b * C_ * N_;
#pragma unroll
    for (int j = 0; j < 6; j++) {
      int g = w * 6 + j;
      if (g < 16) {
        float bvv = bv[16 * g + l15];
#pragma unroll
        for (int nt = 0; nt < 2; nt++) {
          f16x4 vals;
#pragma unroll
          for (int r = 0; r < 4; r++) vals[r] = (f16)(acc[j][nt][r] + bvv);
          *(f16x4*)(vbout + ((size_t)g * 128 + (n0 >> 5)) * TS +
                    l15 * 32 + 16 * nt + 4 * quad) = vals;
        }
      } else {
        int oq = (g < 20) ? (g - 16) : (g - 20);
        const float* bias = (g < 20) ? bq : bk;
        f16* ob = ((g < 20) ? QTt : KTt) + (size_t)b * N_ * CQK;
#pragma unroll
        for (int nt = 0; nt < 2; nt++) {
          f16x4 vals;
#pragma unroll
          for (int r = 0; r < 4; r++)
            vals[r] = (f16)(acc[j][nt][r] + bias[16 * oq + 4 * quad + r]);
          *(f16x4*)(ob + (((size_t)(n0 >> 4) + nt) * 2 + (oq >> 1)) * TS + l15 * 32 +
                    16 * (oq & 1) + 4 * quad) = vals;
        }
      }
    }
  }
  gridbar(bar);

  // ================= phase 2: attn (sb = bid&7 -> XCD-pinned, m0 = bid>>3) ====
  {
    int sb = bid & 7;
    int seg = sb >> 2;
    int b = sb & 3;
    int m0 = (bid >> 3) * 64;
    const f16* qtb = QTt + (size_t)b * N_ * CQK;
    const f16* ktb = KTt + (size_t)b * N_ * CQK;
    const f16* vb = Vt + (size_t)b * C_ * N_;

    f32x4 oacc[4][4];
#pragma unroll
    for (int ct = 0; ct < 4; ct++)
#pragma unroll
      for (int mt = 0; mt < 4; mt++) oacc[ct][mt] = (f32x4){0.f, 0.f, 0.f, 0.f};

    f16x8 kf[4][2];
#pragma unroll
    for (int mt = 0; mt < 4; mt++)
#pragma unroll
      for (int ks = 0; ks < 2; ks++)
        kf[mt][ks] = *(const f16x8*)(ktb + ((size_t)((m0 >> 4) + mt) * 2 + ks) * TS +
                                     TILE_OFF(l15, quad));

    f16x8 qf[2][2];
#pragma unroll
    for (int nt = 0; nt < 2; nt++)
#pragma unroll
      for (int ks = 0; ks < 2; ks++)
        qf[nt][ks] = *(const f16x8*)(qtb +
                                     ((size_t)(((seg * SEGN) >> 4) + 2 * w + nt) * 2 + ks) * TS +
                                     TILE_OFF(l15, quad));

    // ---- prologue: QK(0) -> sPt[0] ----
    {
      char* buf = (char*)sh.sPt[0];
#pragma unroll
      for (int nt = 0; nt < 2; nt++) {
        f32x4 sacc[4];
#pragma unroll
        for (int mt = 0; mt < 4; mt++) sacc[mt] = (f32x4){0.f, 0.f, 0.f, 0.f};
#pragma unroll
        for (int ks = 0; ks < 2; ks++)
#pragma unroll
          for (int mt = 0; mt < 4; mt++)
            sacc[mt] = __builtin_amdgcn_mfma_f32_16x16x32_f16(qf[nt][ks], kf[mt][ks],
                                                              sacc[mt], 0, 0, 0);
#pragma unroll
        for (int mt = 0; mt < 4; mt++) {
          f16x4 p;
#pragma unroll
          for (int r = 0; r < 4; r++) {
            float s = sacc[mt][r];
            p[r] = (f16)(s > 0.0f ? s : (__expf(s) - 1.0f));
          }
          int row = 16 * mt + l15;
          int colb = (64 * w + 32 * nt + 8 * quad) ^ ((row & 7) << 4);
          *(f16x4*)(buf + row * 256 + colb) = p;
        }
      }
    }
    {
      int nq = seg * SEGN + NB;
#pragma unroll
      for (int nt = 0; nt < 2; nt++)
#pragma unroll
        for (int ks = 0; ks < 2; ks++)
          qf[nt][ks] = *(const f16x8*)(qtb +
                                       ((size_t)((nq >> 4) + 2 * w + nt) * 2 + ks) * TS +
                                       TILE_OFF(l15, quad));
    }
    __syncthreads();

    for (int it = 0; it < ITERS; it++) {
      int n0 = seg * SEGN + it * NB;
      char* rbuf = (char*)sh.sPt[it & 1];
      char* wbuf = (char*)sh.sPt[(it + 1) & 1];
      bool hasNext = (it + 1 < ITERS);

      f16x8 vfA[2][4];
#pragma unroll
      for (int ks = 0; ks < 2; ks++)
#pragma unroll
        for (int ct = 0; ct < 4; ct++)
          vfA[ks][ct] = *(const f16x8*)(vb +
                                        ((size_t)(4 * w + ct) * 128 + (n0 >> 5) + ks) * TS +
                                        TILE_OFF(l15, quad));

      f32x4 s0[4], s1[4];
      if (hasNext) {
#pragma unroll
        for (int mt = 0; mt < 4; mt++) s0[mt] = (f32x4){0.f, 0.f, 0.f, 0.f};
#pragma unroll
        for (int ks = 0; ks < 2; ks++)
#pragma unroll
          for (int mt = 0; mt < 4; mt++)
            s0[mt] = __builtin_amdgcn_mfma_f32_16x16x32_f16(qf[0][ks], kf[mt][ks],
                                                            s0[mt], 0, 0, 0);
      }

      f16x8 pa[4];
#pragma unroll
      for (int mt = 0; mt < 4; mt++) {
        int row = 16 * mt + l15;
        pa[mt] = *(const f16x8*)(rbuf + row * 256 + ((quad * 16) ^ ((row & 7) << 4)));
      }
#pragma unroll
      for (int ct = 0; ct < 4; ct++)
#pragma unroll
        for (int mt = 0; mt < 4; mt++)
          oacc[ct][mt] = __builtin_amdgcn_mfma_f32_16x16x32_f16(vfA[0][ct], pa[mt],
                                                                oacc[ct][mt], 0, 0, 0);

      f16x8 vfB[2][4];
#pragma unroll
      for (int ks = 0; ks < 2; ks++)
#pragma unroll
        for (int ct = 0; ct < 4; ct++)
          vfB[ks][ct] = *(const f16x8*)(vb + ((size_t)(4 * w + ct) * 128 + (n0 >> 5) +
                                              2 + ks) * TS +
                                        TILE_OFF(l15, quad));

      if (hasNext) {
#pragma unroll
        for (int mt = 0; mt < 4; mt++) {
          f16x4 p;
#pragma unroll
          for (int r = 0; r < 4; r++) {
            float s = s0[mt][r];
            p[r] = (f16)(s > 0.0f ? s : (__expf(s) - 1.0f));
          }
          int row = 16 * mt + l15;
          int colb = (64 * w + 8 * quad) ^ ((row & 7) << 4);
          *(f16x4*)(wbuf + row * 256 + colb) = p;
        }
      }

#pragma unroll
      for (int mt = 0; mt < 4; mt++) {
        int row = 16 * mt + l15;
        pa[mt] = *(const f16x8*)(rbuf + row * 256 + ((64 + quad * 16) ^ ((row & 7) << 4)));
      }
#pragma unroll
      for (int ct = 0; ct < 4; ct++)
#pragma unroll
        for (int mt = 0; mt < 4; mt++)
          oacc[ct][mt] = __builtin_amdgcn_mfma_f32_16x16x32_f16(vfA[1][ct], pa[mt],
                                                                oacc[ct][mt], 0, 0, 0);

      if (hasNext) {
#pragma unroll
        for (int mt = 0; mt < 4; mt++) s1[mt] = (f32x4){0.f, 0.f, 0.f, 0.f};
#pragma unroll
        for (int ks = 0; ks < 2; ks++)
#pragma unroll
          for (int mt = 0; mt < 4; mt++)
            s1[mt] = __builtin_amdgcn_mfma_f32_16x16x32_f16(qf[1][ks], kf[mt][ks],
                                                            s1[mt], 0, 0, 0);
      }

#pragma unroll
      for (int mt = 0; mt < 4; mt++) {
        int row = 16 * mt + l15;
        pa[mt] = *(const f16x8*)(rbuf + row * 256 + ((128 + quad * 16) ^ ((row & 7) << 4)));
      }
#pragma unroll
      for (int ct = 0; ct < 4; ct++)
#pragma unroll
        for (int mt = 0; mt < 4; mt++)
          oacc[ct][mt] = __builtin_amdgcn_mfma_f32_16x16x32_f16(vfB[0][ct], pa[mt],
                                                                oacc[ct][mt], 0, 0, 0);

      if (hasNext) {
#pragma unroll
        for (int mt = 0; mt < 4; mt++) {
          f16x4 p;
#pragma unroll
          for (int r = 0; r < 4; r++) {
            float s = s1[mt][r];
            p[r] = (f16)(s > 0.0f ? s : (__expf(s) - 1.0f));
          }
          int row = 16 * mt + l15;
          int colb = (64 * w + 32 + 8 * quad) ^ ((row & 7) << 4);
          *(f16x4*)(wbuf + row * 256 + colb) = p;
        }
        if (it + 2 < ITERS) {
          int nq = seg * SEGN + (it + 2) * NB;
#pragma unroll
          for (int nt = 0; nt < 2; nt++)
#pragma unroll
            for (int ks = 0; ks < 2; ks++)
              qf[nt][ks] = *(const f16x8*)(qtb +
                                           ((size_t)((nq >> 4) + 2 * w + nt) * 2 + ks) * TS +
                                           TILE_OFF(l15, quad));
        }
      }

#pragma unroll
      for (int mt = 0; mt < 4; mt++) {
        int row = 16 * mt + l15;
        pa[mt] = *(const f16x8*)(rbuf + row * 256 + ((192 + quad * 16) ^ ((row & 7) << 4)));
      }
#pragma unroll
      for (int ct = 0; ct < 4; ct++)
#pragma unroll
        for (int mt = 0; mt < 4; mt++)
          oacc[ct][mt] = __builtin_amdgcn_mfma_f32_16x16x32_f16(vfB[1][ct], pa[mt],
                                                                oacc[ct][mt], 0, 0, 0);

      __syncthreads();
    }

    // ---- fused wg projection ----
    f16* obuf = (f16*)sh.sPt;
#pragma unroll
    for (int ct = 0; ct < 4; ct++) {
#pragma unroll
      for (int mt = 0; mt < 4; mt++) {
        f16x4 vals;
#pragma unroll
        for (int r = 0; r < 4; r++)
          vals[r] = (f16)(oacc[ct][mt][r] * (1.0f / (float)N_));
        *(f16x4*)(obuf + (mt * 8 + 2 * w + (ct >> 1)) * TS + l15 * 32 +
                  16 * (ct & 1) + 4 * quad) = vals;
      }
    }
    __syncthreads();
    f32x4 accO[4][4];
#pragma unroll
    for (int ot = 0; ot < 4; ot++)
#pragma unroll
      for (int mt = 0; mt < 4; mt++) accO[ot][mt] = (f32x4){0.f, 0.f, 0.f, 0.f};
#pragma unroll
    for (int kt = 0; kt < 8; kt++) {
      f16x8 bO[4];
#pragma unroll
      for (int mt = 0; mt < 4; mt++)
        bO[mt] = *(const f16x8*)(obuf + (mt * 8 + kt) * TS + TILE_OFF(l15, quad));
#pragma unroll
      for (int ot = 0; ot < 4; ot++) {
        f16x8 af = *(const f16x8*)(WGt + ((size_t)(4 * w + ot) * 8 + kt) * TS +
                                   TILE_OFF(l15, quad));
#pragma unroll
        for (int mt = 0; mt < 4; mt++)
          accO[ot][mt] = __builtin_amdgcn_mfma_f32_16x16x32_f16(af, bO[mt], accO[ot][mt],
                                                                0, 0, 0);
      }
    }
    f16* pb = part + ((size_t)(seg * B_ + b) * C_) * N_;
#pragma unroll
    for (int ot = 0; ot < 4; ot++) {
#pragma unroll
      for (int mt = 0; mt < 4; mt++) {
        int m = m0 + 16 * mt + l15;
#pragma unroll
        for (int r = 0; r < 4; r++) {
          int o = 64 * w + 16 * ot + 4 * quad + r;
          pb[(size_t)o * N_ + m] = (f16)accO[ot][mt][r];
        }
      }
    }
  }
  gridbar(bar);

  // ================= phase 3: combine (grid-stride x4) =================
  {
    for (int r = 0; r < 4; r++) {
      size_t i = (((size_t)r * NBLK + bid) * 256 + tid) * 8;
      f16x8 p0 = *(const f16x8*)(part + i);
      f16x8 p1 = *(const f16x8*)(part + (size_t)B_ * C_ * N_ + i);
      float bgo = bg[(i >> 12) & 255];
      float4v r0, r1;
#pragma unroll
      for (int j = 0; j < 4; j++) r0[j] = (float)p0[j] + (float)p1[j] + bgo;
#pragma unroll
      for (int j = 0; j < 4; j++) r1[j] = (float)p0[4 + j] + (float)p1[4 + j] + bgo;
      *(float4v*)(out + i) = r0;
      *(float4v*)(out + i + 4) = r1;
    }
  }
}

extern "C" void kernel_launch(void* const* d_in, const int* in_sizes, int n_in,
                              void* d_out, int out_size, void* d_ws, size_t ws_size,
                              hipStream_t stream) {
  const float* x = (const float*)d_in[0];
  const float* wq = (const float*)d_in[1];
  const float* bq = (const float*)d_in[2];
  const float* wk = (const float*)d_in[3];
  const float* bk = (const float*)d_in[4];
  const float* wv = (const float*)d_in[5];
  const float* bv = (const float*)d_in[6];
  const float* wg = (const float*)d_in[7];
  const float* bg = (const float*)d_in[8];
  float* out = (float*)d_out;

  char* ws = (char*)d_ws;
  unsigned* bar = (unsigned*)ws; ws += 64;                           // barrier state
  f16* QTt = (f16*)ws; ws += (size_t)B_ * N_ * CQK * sizeof(f16);   // 2.1 MB
  f16* KTt = (f16*)ws; ws += (size_t)B_ * N_ * CQK * sizeof(f16);   // 2.1 MB
  f16* Vt  = (f16*)ws; ws += (size_t)B_ * C_ * N_ * sizeof(f16);    // 8.4 MB
  f16* WQt = (f16*)ws; ws += (size_t)CQK * C_ * sizeof(f16);
  f16* WKt = (f16*)ws; ws += (size_t)CQK * C_ * sizeof(f16);
  f16* WVt = (f16*)ws; ws += (size_t)C_ * C_ * sizeof(f16);
  f16* WGt = (f16*)ws; ws += (size_t)C_ * C_ * sizeof(f16);
  f16* PART = (f16*)ws; ws += (size_t)SEG * B_ * C_ * N_ * sizeof(f16);  // 16.8 MB

  hipMemsetAsync(bar, 0, 64, stream);
  fused<<<dim3(NBLK), 256, 0, stream>>>(x, wq, bq, wk, bk, wv, bv, wg, bg,
                                        QTt, KTt, Vt, WQt, WKt, WVt, WGt,
                                        PART, out, bar);
}

// Round 9
// 156.931 us; speedup vs baseline: 2.5483x; 2.5483x over previous
//
#include <hip/hip_runtime.h>

#define B_ 4
#define C_ 256
#define CQK 64
#define N_ 4096
#define SEG 2
#define SEGN (N_ / SEG)    // 2048
#define NB 128
#define ITERS (SEGN / NB)  // 16
#define TS 512             // elements per 16x32 fragment tile (1 KB)

typedef _Float16 f16;
typedef __attribute__((ext_vector_type(8))) _Float16 f16x8;
typedef __attribute__((ext_vector_type(4))) _Float16 f16x4;
typedef __attribute__((ext_vector_type(4))) float f32x4;
typedef __attribute__((ext_vector_type(4))) float float4v;

// Fragment-tiled layouts: matrix [R][K] stored as [R/16][K/32] tiles of
// [16][32] f16; wave fragment load = 64 lanes x 16 B over one 1 KB tile.
#define TILE_OFF(l15, quad) ((l15) * 32 + (quad) * 8)

// ---------------- K0: weights fp32 -> fragment-tiled f16 ----------------
__global__ __launch_bounds__(256) void prep_w(
    const float* __restrict__ wq, const float* __restrict__ wk,
    const float* __restrict__ wv, const float* __restrict__ wg,
    f16* __restrict__ WQt, f16* __restrict__ WKt, f16* __restrict__ WVt,
    f16* __restrict__ WGt) {
  int chunk = blockIdx.x * 256 + threadIdx.x;
  if (chunk >= 20480) return;
  const float* src;
  f16* dst;
  int lo;
  if (chunk < 2048) { src = wq; dst = WQt; lo = chunk * 8; }
  else if (chunk < 4096) { src = wk; dst = WKt; lo = (chunk - 2048) * 8; }
  else if (chunk < 12288) { src = wv; dst = WVt; lo = (chunk - 4096) * 8; }
  else { src = wg; dst = WGt; lo = (chunk - 12288) * 8; }
  int o = lo >> 8, k = lo & 255;
  f16x8 v;
#pragma unroll
  for (int j = 0; j < 8; j++) v[j] = (f16)src[lo + j];
  *(f16x8*)(dst + ((size_t)(o >> 4) * 8 + (k >> 5)) * TS + (o & 15) * 32 + (k & 31)) = v;
}

// ---------------- K1: fused transpose + Q/K/V projection (v1, r5 best) ------
// grid: (N/64, B), 512 thr (8 waves). 24 output-tile tasks, 3 per wave.
// (r6 v2 and r7 v3 rewrites both measured slower in total; v1 restored.)
__global__ __launch_bounds__(512) void proj(
    const float* __restrict__ x, const f16* __restrict__ WQt,
    const f16* __restrict__ WKt, const f16* __restrict__ WVt,
    const float* __restrict__ bq, const float* __restrict__ bk,
    const float* __restrict__ bv, f16* __restrict__ QTt, f16* __restrict__ KTt,
    f16* __restrict__ Vt) {
  __shared__ float xs[64][65];    // fp32 transpose stage (64n x 64c chunk)
  __shared__ f16 xt[4 * 8 * TS];  // x strip tiled: [nt 4][kt 8][16 n][32 c]
  int n0 = blockIdx.x * 64;
  int b = blockIdx.y;
  int tid = threadIdx.x, lane = tid & 63, w = tid >> 6;  // w 0..7
  int l15 = lane & 15, quad = lane >> 4;
  const float* xb = x + (size_t)b * C_ * N_;

  for (int cc = 0; cc < 4; cc++) {
#pragma unroll
    for (int i = 0; i < 8; i++)
      xs[lane][w * 8 + i] = xb[(size_t)(cc * 64 + w * 8 + i) * N_ + n0 + lane];
    __syncthreads();
    {
      int nt = w >> 1;
      f16x8 v;
#pragma unroll
      for (int j = 0; j < 8; j++)
        v[j] = (f16)xs[nt * 16 + l15][32 * (w & 1) + quad * 8 + j];
      *(f16x8*)(xt + (nt * 8 + cc * 2 + (w & 1)) * TS + l15 * 32 + quad * 8) = v;
    }
    __syncthreads();
  }

  f32x4 acc[3][4];  // [task j][nt]
#pragma unroll
  for (int j = 0; j < 3; j++)
#pragma unroll
    for (int nt = 0; nt < 4; nt++) acc[j][nt] = (f32x4){0.f, 0.f, 0.f, 0.f};

#pragma unroll
  for (int kt = 0; kt < 8; kt++) {
    f16x8 xf[4];
#pragma unroll
    for (int nt = 0; nt < 4; nt++)
      xf[nt] = *(const f16x8*)(xt + (nt * 8 + kt) * TS + TILE_OFF(l15, quad));
#pragma unroll
    for (int j = 0; j < 3; j++) {
      int g = w * 3 + j;  // wave-uniform
      const f16* Wt;
      int ot;
      bool isV = g < 16;
      if (isV) { Wt = WVt; ot = g; }
      else if (g < 20) { Wt = WQt; ot = g - 16; }
      else { Wt = WKt; ot = g - 20; }
      f16x8 wf = *(const f16x8*)(Wt + ((size_t)ot * 8 + kt) * TS + TILE_OFF(l15, quad));
#pragma unroll
      for (int nt = 0; nt < 4; nt++)
        acc[j][nt] = isV
            ? __builtin_amdgcn_mfma_f32_16x16x32_f16(xf[nt], wf, acc[j][nt], 0, 0, 0)
            : __builtin_amdgcn_mfma_f32_16x16x32_f16(wf, xf[nt], acc[j][nt], 0, 0, 0);
    }
  }

  f16* vbout = Vt + (size_t)b * C_ * N_;
#pragma unroll
  for (int j = 0; j < 3; j++) {
    int g = w * 3 + j;
    if (g < 16) {
      float bvv = bv[16 * g + l15];
#pragma unroll
      for (int nt = 0; nt < 4; nt++) {
        f16x4 vals;
#pragma unroll
        for (int r = 0; r < 4; r++) vals[r] = (f16)(acc[j][nt][r] + bvv);
        *(f16x4*)(vbout + ((size_t)g * 128 + (n0 >> 5) + (nt >> 1)) * TS +
                  l15 * 32 + 16 * (nt & 1) + 4 * quad) = vals;
      }
    } else {
      int oq = (g < 20) ? (g - 16) : (g - 20);
      const float* bias = (g < 20) ? bq : bk;
      f16* ob = ((g < 20) ? QTt : KTt) + (size_t)b * N_ * CQK;
#pragma unroll
      for (int nt = 0; nt < 4; nt++) {
        f16x4 vals;
#pragma unroll
        for (int r = 0; r < 4; r++)
          vals[r] = (f16)(acc[j][nt][r] + bias[16 * oq + 4 * quad + r]);
        *(f16x4*)(ob + (((size_t)(n0 >> 4) + nt) * 2 + (oq >> 1)) * TS + l15 * 32 +
                  16 * (oq & 1) + 4 * quad) = vals;
      }
    }
  }
}

// ---------------- K2: fused attention + wg proj (r5 core + PURE stagger) ----
// grid: (8, 64). blockIdx.x = seg*4+b (XCD-pinned via %8), 4 waves.
// r4 bundled stagger WITH an atomic epilogue (+16us mechanically); the
// regression was mis-attributed. Phase-lock theory stands unfalsified:
// co-resident blocks (same XCD, y differing by 1 or 32 per CU round-robin)
// run identical per-iter schedules and burst the same pipe simultaneously.
// PURE stagger: start the commutative n-loop 8 iters apart for one block of
// each candidate pair — key ((y>>5)^y)&1 covers both pairings. V slices stay
// L2-resident regardless (seg-V = 1 MB << 4 MB XCD L2). No other change.
__global__ __launch_bounds__(256, 2) void attn(const f16* __restrict__ qt,
                                               const f16* __restrict__ kt,
                                               const f16* __restrict__ v,
                                               const f16* __restrict__ WGt,
                                               f16* __restrict__ part) {
  __shared__ __align__(16) f16 sPt[2][64][128];  // P^T dbuf (32 KB); reused as O buf
  int sb = blockIdx.x;
  int seg = sb >> 2;
  int b = sb & 3;
  int m0 = blockIdx.y * 64;
  int it0 = (((blockIdx.y >> 5) ^ blockIdx.y) & 1) * (ITERS / 2);
  int tid = threadIdx.x, lane = tid & 63, w = tid >> 6;
  int l15 = lane & 15, quad = lane >> 4;
  const f16* qtb = qt + (size_t)b * N_ * CQK;
  const f16* ktb = kt + (size_t)b * N_ * CQK;
  const f16* vb = v + (size_t)b * C_ * N_;

  f32x4 oacc[4][4];
#pragma unroll
  for (int ct = 0; ct < 4; ct++)
#pragma unroll
    for (int mt = 0; mt < 4; mt++) oacc[ct][mt] = (f32x4){0.f, 0.f, 0.f, 0.f};

  f16x8 kf[4][2];
#pragma unroll
  for (int mt = 0; mt < 4; mt++)
#pragma unroll
    for (int ks = 0; ks < 2; ks++)
      kf[mt][ks] = *(const f16x8*)(ktb + ((size_t)((m0 >> 4) + mt) * 2 + ks) * TS +
                                   TILE_OFF(l15, quad));

  f16x8 qf[2][2];
  {
    int nq = seg * SEGN + it0 * NB;
#pragma unroll
    for (int nt = 0; nt < 2; nt++)
#pragma unroll
      for (int ks = 0; ks < 2; ks++)
        qf[nt][ks] = *(const f16x8*)(qtb +
                                     ((size_t)((nq >> 4) + 2 * w + nt) * 2 + ks) * TS +
                                     TILE_OFF(l15, quad));
  }

  // ---- prologue: QK(it0) -> sPt[0] ----
  {
    char* buf = (char*)sPt[0];
#pragma unroll
    for (int nt = 0; nt < 2; nt++) {
      f32x4 sacc[4];
#pragma unroll
      for (int mt = 0; mt < 4; mt++) sacc[mt] = (f32x4){0.f, 0.f, 0.f, 0.f};
#pragma unroll
      for (int ks = 0; ks < 2; ks++)
#pragma unroll
        for (int mt = 0; mt < 4; mt++)
          sacc[mt] = __builtin_amdgcn_mfma_f32_16x16x32_f16(qf[nt][ks], kf[mt][ks],
                                                            sacc[mt], 0, 0, 0);
#pragma unroll
      for (int mt = 0; mt < 4; mt++) {
        f16x4 p;
#pragma unroll
        for (int r = 0; r < 4; r++) {
          float s = sacc[mt][r];
          p[r] = (f16)(s > 0.0f ? s : (__expf(s) - 1.0f));
        }
        int row = 16 * mt + l15;
        int colb = (64 * w + 32 * nt + 8 * quad) ^ ((row & 7) << 4);
        *(f16x4*)(buf + row * 256 + colb) = p;
      }
    }
  }
  // prefetch qf for i=1 (iteration index (it0+1)&15)
  {
    int nq = seg * SEGN + ((it0 + 1) & (ITERS - 1)) * NB;
#pragma unroll
    for (int nt = 0; nt < 2; nt++)
#pragma unroll
      for (int ks = 0; ks < 2; ks++)
        qf[nt][ks] = *(const f16x8*)(qtb +
                                     ((size_t)((nq >> 4) + 2 * w + nt) * 2 + ks) * TS +
                                     TILE_OFF(l15, quad));
  }
  __syncthreads();

  for (int i = 0; i < ITERS; i++) {
    int it = (i + it0) & (ITERS - 1);
    int n0 = seg * SEGN + it * NB;
    char* rbuf = (char*)sPt[i & 1];        // P(i), read by PV
    char* wbuf = (char*)sPt[(i + 1) & 1];  // P(i+1), written by QK
    bool hasNext = (i + 1 < ITERS);

    f16x8 vfA[2][4];
#pragma unroll
    for (int ks = 0; ks < 2; ks++)
#pragma unroll
      for (int ct = 0; ct < 4; ct++)
        vfA[ks][ct] = *(const f16x8*)(vb +
                                      ((size_t)(4 * w + ct) * 128 + (n0 >> 5) + ks) * TS +
                                      TILE_OFF(l15, quad));

    // QK(i+1) nt=0 accumulate (interleaves with PV phase 0 below)
    f32x4 s0[4], s1[4];
    if (hasNext) {
#pragma unroll
      for (int mt = 0; mt < 4; mt++) s0[mt] = (f32x4){0.f, 0.f, 0.f, 0.f};
#pragma unroll
      for (int ks = 0; ks < 2; ks++)
#pragma unroll
        for (int mt = 0; mt < 4; mt++)
          s0[mt] = __builtin_amdgcn_mfma_f32_16x16x32_f16(qf[0][ks], kf[mt][ks],
                                                          s0[mt], 0, 0, 0);
    }

    f16x8 pa[4];
#pragma unroll
    for (int mt = 0; mt < 4; mt++) {
      int row = 16 * mt + l15;
      pa[mt] = *(const f16x8*)(rbuf + row * 256 + ((quad * 16) ^ ((row & 7) << 4)));
    }
#pragma unroll
    for (int ct = 0; ct < 4; ct++)
#pragma unroll
      for (int mt = 0; mt < 4; mt++)
        oacc[ct][mt] = __builtin_amdgcn_mfma_f32_16x16x32_f16(vfA[0][ct], pa[mt],
                                                              oacc[ct][mt], 0, 0, 0);

    f16x8 vfB[2][4];
#pragma unroll
    for (int ks = 0; ks < 2; ks++)
#pragma unroll
      for (int ct = 0; ct < 4; ct++)
        vfB[ks][ct] = *(const f16x8*)(vb + ((size_t)(4 * w + ct) * 128 + (n0 >> 5) +
                                            2 + ks) * TS +
                                      TILE_OFF(l15, quad));

    // elu+pack+write for nt=0 (VALU; interleaves with PV MFMA around it)
    if (hasNext) {
#pragma unroll
      for (int mt = 0; mt < 4; mt++) {
        f16x4 p;
#pragma unroll
        for (int r = 0; r < 4; r++) {
          float s = s0[mt][r];
          p[r] = (f16)(s > 0.0f ? s : (__expf(s) - 1.0f));
        }
        int row = 16 * mt + l15;
        int colb = (64 * w + 8 * quad) ^ ((row & 7) << 4);
        *(f16x4*)(wbuf + row * 256 + colb) = p;
      }
    }

#pragma unroll
    for (int mt = 0; mt < 4; mt++) {
      int row = 16 * mt + l15;
      pa[mt] = *(const f16x8*)(rbuf + row * 256 + ((64 + quad * 16) ^ ((row & 7) << 4)));
    }
#pragma unroll
    for (int ct = 0; ct < 4; ct++)
#pragma unroll
      for (int mt = 0; mt < 4; mt++)
        oacc[ct][mt] = __builtin_amdgcn_mfma_f32_16x16x32_f16(vfA[1][ct], pa[mt],
                                                              oacc[ct][mt], 0, 0, 0);

    // QK(i+1) nt=1 accumulate
    if (hasNext) {
#pragma unroll
      for (int mt = 0; mt < 4; mt++) s1[mt] = (f32x4){0.f, 0.f, 0.f, 0.f};
#pragma unroll
      for (int ks = 0; ks < 2; ks++)
#pragma unroll
        for (int mt = 0; mt < 4; mt++)
          s1[mt] = __builtin_amdgcn_mfma_f32_16x16x32_f16(qf[1][ks], kf[mt][ks],
                                                          s1[mt], 0, 0, 0);
    }

#pragma unroll
    for (int mt = 0; mt < 4; mt++) {
      int row = 16 * mt + l15;
      pa[mt] = *(const f16x8*)(rbuf + row * 256 + ((128 + quad * 16) ^ ((row & 7) << 4)));
    }
#pragma unroll
    for (int ct = 0; ct < 4; ct++)
#pragma unroll
      for (int mt = 0; mt < 4; mt++)
        oacc[ct][mt] = __builtin_amdgcn_mfma_f32_16x16x32_f16(vfB[0][ct], pa[mt],
                                                              oacc[ct][mt], 0, 0, 0);

    // elu+pack+write for nt=1, then qf prefetch for i+2
    if (hasNext) {
#pragma unroll
      for (int mt = 0; mt < 4; mt++) {
        f16x4 p;
#pragma unroll
        for (int r = 0; r < 4; r++) {
          float s = s1[mt][r];
          p[r] = (f16)(s > 0.0f ? s : (__expf(s) - 1.0f));
        }
        int row = 16 * mt + l15;
        int colb = (64 * w + 32 + 8 * quad) ^ ((row & 7) << 4);
        *(f16x4*)(wbuf + row * 256 + colb) = p;
      }
      if (i + 2 < ITERS) {
        int nq = seg * SEGN + ((i + 2 + it0) & (ITERS - 1)) * NB;
#pragma unroll
        for (int nt = 0; nt < 2; nt++)
#pragma unroll
          for (int ks = 0; ks < 2; ks++)
            qf[nt][ks] = *(const f16x8*)(qtb +
                                         ((size_t)((nq >> 4) + 2 * w + nt) * 2 + ks) * TS +
                                         TILE_OFF(l15, quad));
      }
    }

#pragma unroll
    for (int mt = 0; mt < 4; mt++) {
      int row = 16 * mt + l15;
      pa[mt] = *(const f16x8*)(rbuf + row * 256 + ((192 + quad * 16) ^ ((row & 7) << 4)));
    }
#pragma unroll
    for (int ct = 0; ct < 4; ct++)
#pragma unroll
      for (int mt = 0; mt < 4; mt++)
        oacc[ct][mt] = __builtin_amdgcn_mfma_f32_16x16x32_f16(vfB[1][ct], pa[mt],
                                                              oacc[ct][mt], 0, 0, 0);

    __syncthreads();
  }

  // ---- fused wg projection: part[seg] = wg . (O/N), exclusive f16 stores ----
  f16* obuf = (f16*)sPt;
#pragma unroll
  for (int ct = 0; ct < 4; ct++) {
#pragma unroll
    for (int mt = 0; mt < 4; mt++) {
      f16x4 vals;
#pragma unroll
      for (int r = 0; r < 4; r++)
        vals[r] = (f16)(oacc[ct][mt][r] * (1.0f / (float)N_));
      *(f16x4*)(obuf + (mt * 8 + 2 * w + (ct >> 1)) * TS + l15 * 32 +
                16 * (ct & 1) + 4 * quad) = vals;
    }
  }
  __syncthreads();
  f32x4 accO[4][4];
#pragma unroll
  for (int ot = 0; ot < 4; ot++)
#pragma unroll
    for (int mt = 0; mt < 4; mt++) accO[ot][mt] = (f32x4){0.f, 0.f, 0.f, 0.f};
#pragma unroll
  for (int kt = 0; kt < 8; kt++) {
    f16x8 bO[4];
#pragma unroll
    for (int mt = 0; mt < 4; mt++)
      bO[mt] = *(const f16x8*)(obuf + (mt * 8 + kt) * TS + TILE_OFF(l15, quad));
#pragma unroll
    for (int ot = 0; ot < 4; ot++) {
      f16x8 af = *(const f16x8*)(WGt + ((size_t)(4 * w + ot) * 8 + kt) * TS +
                                 TILE_OFF(l15, quad));
#pragma unroll
      for (int mt = 0; mt < 4; mt++)
        accO[ot][mt] = __builtin_amdgcn_mfma_f32_16x16x32_f16(af, bO[mt], accO[ot][mt], 0, 0, 0);
    }
  }
  f16* pb = part + ((size_t)(seg * B_ + b) * C_) * N_;
#pragma unroll
  for (int ot = 0; ot < 4; ot++) {
#pragma unroll
    for (int mt = 0; mt < 4; mt++) {
      int m = m0 + 16 * mt + l15;
#pragma unroll
      for (int r = 0; r < 4; r++) {
        int o = 64 * w + 16 * ot + 4 * quad + r;
        pb[(size_t)o * N_ + m] = (f16)accO[ot][mt][r];
      }
    }
  }
}

// ---------------- K3: out = part0 + part1 + bg ----------------
__global__ __launch_bounds__(256) void combine(const f16* __restrict__ part,
                                               const float* __restrict__ bg,
                                               float* __restrict__ out) {
  size_t i = ((size_t)blockIdx.x * 256 + threadIdx.x) * 8;
  f16x8 p0 = *(const f16x8*)(part + i);
  f16x8 p1 = *(const f16x8*)(part + (size_t)B_ * C_ * N_ + i);
  float bgo = bg[(i >> 12) & 255];
  float4v r0, r1;
#pragma unroll
  for (int j = 0; j < 4; j++) r0[j] = (float)p0[j] + (float)p1[j] + bgo;
#pragma unroll
  for (int j = 0; j < 4; j++) r1[j] = (float)p0[4 + j] + (float)p1[4 + j] + bgo;
  *(float4v*)(out + i) = r0;
  *(float4v*)(out + i + 4) = r1;
}

extern "C" void kernel_launch(void* const* d_in, const int* in_sizes, int n_in,
                              void* d_out, int out_size, void* d_ws, size_t ws_size,
                              hipStream_t stream) {
  const float* x = (const float*)d_in[0];
  const float* wq = (const float*)d_in[1];
  const float* bq = (const float*)d_in[2];
  const float* wk = (const float*)d_in[3];
  const float* bk = (const float*)d_in[4];
  const float* wv = (const float*)d_in[5];
  const float* bv = (const float*)d_in[6];
  const float* wg = (const float*)d_in[7];
  const float* bg = (const float*)d_in[8];
  float* out = (float*)d_out;

  char* ws = (char*)d_ws;
  f16* QTt = (f16*)ws; ws += (size_t)B_ * N_ * CQK * sizeof(f16);   // 2.1 MB
  f16* KTt = (f16*)ws; ws += (size_t)B_ * N_ * CQK * sizeof(f16);   // 2.1 MB
  f16* Vt  = (f16*)ws; ws += (size_t)B_ * C_ * N_ * sizeof(f16);    // 8.4 MB
  f16* WQt = (f16*)ws; ws += (size_t)CQK * C_ * sizeof(f16);
  f16* WKt = (f16*)ws; ws += (size_t)CQK * C_ * sizeof(f16);
  f16* WVt = (f16*)ws; ws += (size_t)C_ * C_ * sizeof(f16);
  f16* WGt = (f16*)ws; ws += (size_t)C_ * C_ * sizeof(f16);
  f16* PART = (f16*)ws; ws += (size_t)SEG * B_ * C_ * N_ * sizeof(f16);  // 16.8 MB

  prep_w<<<dim3(80), 256, 0, stream>>>(wq, wk, wv, wg, WQt, WKt, WVt, WGt);
  proj<<<dim3(N_ / 64, B_), 512, 0, stream>>>(x, WQt, WKt, WVt, bq, bk, bv,
                                              QTt, KTt, Vt);
  attn<<<dim3(SEG * B_, N_ / 64), 256, 0, stream>>>(QTt, KTt, Vt, WGt, PART);
  combine<<<dim3(2048), 256, 0, stream>>>(PART, bg, out);
}